// Round 4
// baseline (784.516 us; speedup 1.0000x reference)
//
#include <hip/hip_runtime.h>

// BaseProtonet: inv_d[n,p] = 1/(mse(f_n,proto_p)+1e-5), labels[n] = plabels[argmax_p inv_d]
// msed = ||f||^2 - 2 f.p + ||p||^2  (= 64*mse), argmax inv_d == argmin msed.
//
// Round 6: thread=proto (coalesced writes, L1-uniform f loads) with the per-row
// reduction cost engineered out.
//  Round-5 PMC: thread=row scattered 16B stores -> WRITE_SIZE 1.07GB = 4.06x ideal
//  (64 lanes x 64 distinct 64B lines per store) at 2.7 TB/s = the 418us. Also LDS
//  proto-broadcast oversubscribed (3072 LDS cyc vs 1280 VALU cyc per epoch) and
//  occupancy 0.85 waves/SIMD. Round-3's thread=proto had IDEAL writes (270MB) and
//  its 492us was the per-row serial reduce (3 butterflies + 2 barriers per row).
//  This round keeps thread=proto and attacks the reduce:
//   - argmin key t = p2 - 2*cross + 1024 (fs drops out: argmin invariant to the
//     row-uniform fs). Positive => quantized u32 key | proto idx, res <=0.031
//     << MARGIN=0.125 (same budget as validated round-2 keys).
//   - merged min butterfly only (6 shfl + 6 v_min_u32); 2nd-min replaced by one
//     __ballot(within-MARGIN) popcount (trigger is conservative-superset).
//   - 8-row batches: 2 barriers per 8 rows; 8 chains pipeline; combine by 8
//     parallel lanes; fs for 8 rows via distributed 2-elem/thread tree (~10 ops).
//   - inv_d value in validated order (fsf - 2c + p2f), rcp+1NR (absmax 0.0039).
//   - fp64 rescue: VERBATIM validated round-2 recipe (same layout, drops in).
//  launch_bounds(256,2) -> 128-VGPR cap (empirical cap=256/arg2), demand ~115
//  (pr 64 + cross[8] + working) -> 4 waves/SIMD, no LDS pressure (<1KB).

#define PROTOS 256
#define DIM 64
#define MARGIN 0.125f
#define BLOCK 256
#define RB 8
#define TOFF 1024.0f

__global__ __launch_bounds__(BLOCK, 2)
void protonet_kernel(const float* __restrict__ feats,
                     const float* __restrict__ protos,
                     const int* __restrict__ plabels,
                     float* __restrict__ out_inv,
                     float* __restrict__ out_lab,
                     int rows_total)
{
    const int p    = threadIdx.x;          // proto index (BLOCK == PROTOS)
    const int lane = threadIdx.x & 63;
    const int wid  = threadIdx.x >> 6;

    // ---- prototype row in 64 VGPRs, pinned (round-3 lesson: block remat) ----
    float pr[DIM];
    {
        const float4* prv = (const float4*)(protos + p * DIM);
        #pragma unroll
        for (int i = 0; i < DIM / 4; ++i) {
            float4 v = prv[i];
            pr[4 * i + 0] = v.x; pr[4 * i + 1] = v.y;
            pr[4 * i + 2] = v.z; pr[4 * i + 3] = v.w;
        }
    }
    #pragma unroll
    for (int k = 0; k < DIM; ++k) asm volatile("" : "+v"(pr[k]));

    // ||p||^2: fp64 serial-k single-acc (exact validated order) + fp32 + offset
    double p2d = 0.0;
    #pragma unroll
    for (int k = 0; k < DIM; ++k) p2d = fma((double)pr[k], (double)pr[k], p2d);
    const float p2f   = (float)p2d;
    const float p2pad = p2f + TOFF;

    __shared__ unsigned int s_m1[RB][4];
    __shared__ unsigned int s_wfl[RB][4];
    __shared__ float        s_fs[RB];
    __shared__ int          s_resc[RB];
    __shared__ double       s_dval[4];
    __shared__ int          s_didx[4];

    const long long nbatch = ((long long)rows_total + RB - 1) / RB;
    for (long long b = blockIdx.x; b < nbatch; b += gridDim.x) {
        const long long row0 = b * RB;

        // ---- fs for 8 rows, distributed: thread t -> row t>>5, elems 2(t&31) ----
        {
            const int r = p >> 5;
            const int e = (p & 31) * 2;
            long long rr = row0 + r;
            if (rr >= rows_total) rr = rows_total - 1;
            float2 fv = *(const float2*)(feats + rr * DIM + e);
            float s = fmaf(fv.x, fv.x, fv.y * fv.y);
            #pragma unroll
            for (int sh = 16; sh > 0; sh >>= 1) s += __shfl_xor(s, sh, 64);
            if ((p & 31) == 0) s_fs[r] = s;    // fs only feeds inv_d values
        }

        // ---- 8 dots + per-row min-butterfly + margin ballot ----
        float cross[RB];
        #pragma unroll 4
        for (int r = 0; r < RB; ++r) {
            long long rr = row0 + r;
            if (rr >= rows_total) rr = rows_total - 1;
            const float4* f4 = (const float4*)(feats + rr * DIM);
            float a0 = 0.f, a1 = 0.f, a2 = 0.f, a3 = 0.f;
            #pragma unroll
            for (int i = 0; i < DIM / 4; ++i) {
                float4 x = f4[i];              // row-uniform load -> L1 broadcast
                a0 = fmaf(x.x, pr[4 * i + 0], a0);
                a1 = fmaf(x.y, pr[4 * i + 1], a1);
                a2 = fmaf(x.z, pr[4 * i + 2], a2);
                a3 = fmaf(x.w, pr[4 * i + 3], a3);
            }
            float c = (a0 + a1) + (a2 + a3);
            cross[r] = c;

            // argmin key: fs-free, positive, quantized, proto idx in low byte
            float t = fmaxf(fmaf(c, -2.0f, p2pad), 0.0f);
            unsigned int key = (__float_as_uint(t) & 0xFFFFFF00u) | (unsigned int)p;
            unsigned int m1 = key;
            #pragma unroll
            for (int sh = 32; sh > 0; sh >>= 1) {
                unsigned int o = __shfl_xor(m1, sh, 64);
                m1 = (o < m1) ? o : m1;
            }
            // near-tie flag: >=2 lanes of this wave within MARGIN of wave-best
            float tb = __uint_as_float(m1 & 0xFFFFFF00u);
            unsigned long long bal = __ballot((t - tb) < MARGIN);
            if (lane == 0) {
                s_m1[r][wid]  = m1;
                s_wfl[r][wid] = (__popcll(bal) >= 2) ? 1u : 0u;
            }
        }
        __syncthreads();

        // ---- cross-wave combine: 8 parallel lanes, one per row ----
        if (p < RB) {
            const int r = p;
            const long long rowg = row0 + r;
            if (rowg < rows_total) {
                unsigned int b1 = 0xFFFFFFFFu;
                #pragma unroll
                for (int w = 0; w < 4; ++w) {
                    unsigned int u = s_m1[r][w];
                    b1 = (u < b1) ? u : b1;
                }
                unsigned int m2 = 0xFFFFFFFFu, fl = 0;
                #pragma unroll
                for (int w = 0; w < 4; ++w) {
                    unsigned int u = s_m1[r][w];
                    if (u == b1) fl = s_wfl[r][w];           // keys globally unique
                    else         m2 = (u < m2) ? u : m2;
                }
                float v1 = __uint_as_float(b1 & 0xFFFFFF00u);
                float v2 = __uint_as_float(m2 & 0xFFFFFF00u);
                int resc = fl || ((v2 - v1) < MARGIN);
                s_resc[r] = resc;
                if (!resc) out_lab[rowg] = (float)plabels[b1 & 0xFFu];
            } else s_resc[r] = 0;
        }

        // ---- inv_d values + coalesced stores (validated order + rcp+1NR) ----
        #pragma unroll
        for (int r = 0; r < RB; ++r) {
            const long long rowg = row0 + r;
            // s_fs written pre-barrier1; barrier below separates next-batch writes
            float m = (s_fs[r] - 2.0f * cross[r]) + p2f;
            float d = fmaf(m, 0.015625f, 1e-5f);
            float rc = __builtin_amdgcn_rcpf(d);
            rc = rc * (2.0f - d * rc);
            if (rowg < rows_total) out_inv[rowg * PROTOS + p] = rc;
        }
        __syncthreads();

        // ---- fp64 rescue (verbatim validated round-2 recipe), ~1.5% of rows ----
        #pragma unroll 1
        for (int r = 0; r < RB; ++r) {
            if (!s_resc[r]) continue;        // block-uniform
            const long long rw = row0 + r;
            const float* fr = feats + rw * DIM;

            float fl = fr[lane];
            double fsd = (double)fl * (double)fl;
            #pragma unroll
            for (int s = 32; s > 0; s >>= 1) fsd += __shfl_xor(fsd, s, 64);

            double d0 = 0.0, d1 = 0.0, d2 = 0.0, d3 = 0.0;
            #pragma unroll
            for (int k = 0; k < DIM; k += 4) {
                d0 = fma((double)fr[k + 0], (double)pr[k + 0], d0);
                d1 = fma((double)fr[k + 1], (double)pr[k + 1], d1);
                d2 = fma((double)fr[k + 2], (double)pr[k + 2], d2);
                d3 = fma((double)fr[k + 3], (double)pr[k + 3], d3);
            }
            double crossd = (d0 + d1) + (d2 + d3);
            double msedd  = fsd - 2.0 * crossd + p2d;

            double bv = msedd;
            int    bi = p;
            #pragma unroll
            for (int s = 32; s > 0; s >>= 1) {
                double ov = __shfl_xor(bv, s, 64);
                int    oi = __shfl_xor(bi, s, 64);
                if (ov < bv || (ov == bv && oi < bi)) { bv = ov; bi = oi; }
            }
            if (lane == 0) { s_dval[wid] = bv; s_didx[wid] = bi; }
            __syncthreads();
            if (threadIdx.x == 0) {
                double v = s_dval[0];
                int    i = s_didx[0];
                #pragma unroll
                for (int w = 1; w < 4; ++w) {
                    if (s_dval[w] < v || (s_dval[w] == v && s_didx[w] < i)) {
                        v = s_dval[w]; i = s_didx[w];
                    }
                }
                out_lab[rw] = (float)plabels[i];
            }
            __syncthreads();
        }
    }
}

extern "C" void kernel_launch(void* const* d_in, const int* in_sizes, int n_in,
                              void* d_out, int out_size, void* d_ws, size_t ws_size,
                              hipStream_t stream) {
    const float* feats  = (const float*)d_in[0];
    const float* protos = (const float*)d_in[1];
    const int*   plab   = (const int*)d_in[2];
    const int rows = in_sizes[0] / DIM;

    float* out_inv = (float*)d_out;
    float* out_lab = out_inv + (size_t)rows * PROTOS;

    dim3 grid(2048), block(BLOCK);
    hipLaunchKernelGGL(protonet_kernel, grid, block, 0, stream,
                       feats, protos, plab, out_inv, out_lab, rows);
}